// Round 9
// baseline (54.890 us; speedup 1.0000x reference)
//
#include <hip/hip_runtime.h>
#include <stdint.h>

// Problem constants
#define B_  32
#define S_  512
#define C_  320
#define H_  512
#define NROW (B_*C_)          // 10240 rows, enumerated in SCRAMBLED order n' = c*32 + b

typedef __attribute__((ext_vector_type(8))) short short8;
typedef __attribute__((ext_vector_type(4))) float f32x4;

__device__ __forceinline__ unsigned short f2bf(float x){
  unsigned u = __builtin_bit_cast(unsigned, x);
  u = u + 0x7FFFu + ((u >> 16) & 1u);          // round-to-nearest-even
  return (unsigned short)(u >> 16);
}
__device__ __forceinline__ float sigf(float x){ return 1.0f/(1.0f + __expf(-x)); }
__device__ __forceinline__ float tanh_fast(float x){ return 2.0f/(1.0f + __expf(-2.0f*x)) - 1.0f; }

__device__ __forceinline__ void gload16(const void* g, void* l){
  __builtin_amdgcn_global_load_lds((const __attribute__((address_space(1))) void*)g,
                                   (__attribute__((address_space(3))) void*)l, 16, 0, 0);
}

// ---- Pass 0 (fused): blocks 0..767 cast w_ih; blocks 768..2047 cast+T x ----
// x part writes xws2[n'][s], n' = c*32 + b  (scramble folded into the layout,
// so the GEMM's N dimension IS the output row order).
__global__ __launch_bounds__(256) void k_prep(const float* __restrict__ w,
                                              const float* __restrict__ x,
                                              unsigned short* __restrict__ aws,
                                              unsigned short* __restrict__ xws){
  const int bidg = blockIdx.x;
  const int tid = threadIdx.x;
  if (bidg < 768){
    // compact+cast w_ih rows {i:0-511, g:1024-1535, o:1536-2047} -> aws[3][512][512]
    int flat = bidg*256 + tid;                 // float4 units; 3*512*512/4 = 196608
    int plane = flat >> 16;
    int rem   = flat & 65535;
    int srow  = (plane == 0 ? 0 : (plane == 1 ? 1024 : 1536));
    float4 v = ((const float4*)w)[srow*128 + rem];
    uint2 p;
    p.x = (unsigned)f2bf(v.x) | ((unsigned)f2bf(v.y) << 16);
    p.y = (unsigned)f2bf(v.z) | ((unsigned)f2bf(v.w) << 16);
    ((uint2*)aws)[flat] = p;
    return;
  }
  // x (b,s,c) f32 -> xws2[c*32+b][s] bf16 (64x64 LDS transpose tile)
  __shared__ float lds[64][65];
  const int idx = bidg - 768;                  // 0..1279 = st + 8*ctt + 40*b
  const int st = idx & 7;
  const int r5 = idx >> 3;
  const int ctt = r5 % 5, b = r5 / 5;
  const int s0 = st*64, c0 = ctt*64;
  const int row = tid >> 2, q = tid & 3;

  const float* src = x + ((size_t)(b*S_ + s0 + row))*C_ + c0 + q*16;
  #pragma unroll
  for (int j = 0; j < 4; j++){
    float4 v = ((const float4*)src)[j];
    lds[row][q*16 + j*4 + 0] = v.x;
    lds[row][q*16 + j*4 + 1] = v.y;
    lds[row][q*16 + j*4 + 2] = v.z;
    lds[row][q*16 + j*4 + 3] = v.w;
  }
  __syncthreads();
  const int crow = row;
  const size_t nprime = (size_t)(c0 + crow)*32 + (size_t)b;   // scrambled row
  #pragma unroll
  for (int j = 0; j < 2; j++){
    short8 o;
    #pragma unroll
    for (int e = 0; e < 8; e++)
      o[e] = (short)f2bf(lds[q*16 + j*8 + e][crow]);
    *(short8*)(xws + nprime*S_ + s0 + q*16 + j*8) = o;
  }
}

// ---- Pass 1: MFMA GEMM + LSTM-cell epilogue + fused output transpose -------
// GEMM: M=1536 (3 gates x 512 k), N=10240 (n' = c*32+b, scrambled order), K=512.
// Tile BM=192 x BN=128 x BK=64, 256 thr = 4 waves (2M x 2N, 4 N-frags),
// single-buffered 40KB LDS, 2 barriers/K-step, 4 blocks/CU (m97 regime).
// Epilogue: h-tile (128 n' x 64 k) -> LDS f32 transpose -> DIRECT f32 out
// writes, 512B-contiguous c2 runs. No hws, no k_out, one flush boundary total.
__global__ __launch_bounds__(256, 4) void k_gemm(const unsigned short* __restrict__ aws,
                                                 const unsigned short* __restrict__ xws,
                                                 const float* __restrict__ b_ih,
                                                 const float* __restrict__ b_hh,
                                                 float* __restrict__ out){
  // A [3][64 krow][128B swz] at 0..24576; B [128 nrow][128B swz] at 24576..40960
  // epilogue reuses as float tr[128][68] (34816 B)
  __shared__ alignas(16) char lds[40960];

  const int tid  = threadIdx.x;
  const int w    = tid >> 6;
  const int lane = tid & 63;
  const int wm = w >> 1, wn = w & 1;

  // decode: bid = n2*64 + kt*8 + x8; nt = n2*8 + x8 (fixed XCD walks kt at
  // constant nt -> B-slice L2 reuse)
  const int bid = blockIdx.x;                  // 0..639
  const int x8 = bid & 7, y = bid >> 3;
  const int kt = y & 7, n2 = y >> 3;
  const int nt = n2*8 + x8;
  const int k0 = kt*64;
  const int nbase = nt*128;

  f32x4 acc[3][2][4];
  #pragma unroll
  for (int gi = 0; gi < 3; gi++)
    #pragma unroll
    for (int mf = 0; mf < 2; mf++)
      #pragma unroll
      for (int nf = 0; nf < 4; nf++)
        acc[gi][mf][nf] = (f32x4){0.f, 0.f, 0.f, 0.f};

  // staging: each global_load_lds = 1024B = 8 rows x 128B.
  // LDS slot (row, colb) holds global element (row, colb ^ ((row&7)<<4)).
  const int cr   = lane >> 3;
  const int slot = ((lane & 7) ^ cr) << 4;

  // 40 chunks (24 A + 16 B), 10 per wave; 32-bit offsets from ws base (=aws)
  const char* wsb = (const char*)aws;
  unsigned srcoff[10];
  int      dstoff[10];
  #pragma unroll
  for (int i = 0; i < 10; i++){
    int q = w*10 + i;
    if (q < 24){
      int gi = q >> 3, q8 = q & 7;
      int grow = gi*512 + k0 + q8*8 + cr;
      srcoff[i] = (unsigned)(grow*1024 + slot);              // aws at ws+0
      dstoff[i] = gi*8192 + q8*1024;
    } else {
      int q8 = q - 24;                                       // 0..15
      int xrow = nbase + q8*8 + cr;                          // xws2 row == n'
      srcoff[i] = (unsigned)(2097152 + xrow*1024 + slot);    // xws2 at ws+2MiB
      dstoff[i] = 24576 + q8*1024;
    }
  }

  const int lo16 = (lane >> 4) << 4;
  const int swz  = (lane & 7) << 4;
  const int l15  = lane & 15;

  for (int t = 0; t < 8; t++){
    #pragma unroll
    for (int i = 0; i < 10; i++){
      gload16(wsb + (size_t)srcoff[i], &lds[0] + dstoff[i]);
      srcoff[i] += 128;
    }
    __syncthreads();                           // stage t complete
    #pragma unroll
    for (int ks = 0; ks < 2; ks++){
      const int colb = (ks*64 + lo16) ^ swz;
      short8 aF[3][2], bF[4];
      #pragma unroll
      for (int gi = 0; gi < 3; gi++)
        #pragma unroll
        for (int mf = 0; mf < 2; mf++)
          aF[gi][mf] = *(const short8*)(&lds[0] + gi*8192 + (wm*32 + mf*16 + l15)*128 + colb);
      #pragma unroll
      for (int nf = 0; nf < 4; nf++)
        bF[nf] = *(const short8*)(&lds[0] + 24576 + (wn*64 + nf*16 + l15)*128 + colb);
      #pragma unroll
      for (int gi = 0; gi < 3; gi++)
        #pragma unroll
        for (int mf = 0; mf < 2; mf++)
          #pragma unroll
          for (int nf = 0; nf < 4; nf++)
            acc[gi][mf][nf] = __builtin_amdgcn_mfma_f32_16x16x32_bf16(aF[gi][mf], bF[nf], acc[gi][mf][nf], 0, 0, 0);
    }
    __syncthreads();                           // reads done before next stage
  }

  // ---- epilogue: gates -> h -> LDS f32 [128 n'][68] -> coalesced out ----
  float* tr = (float*)&lds[0];
  #pragma unroll
  for (int mf = 0; mf < 2; mf++){
    const int kl = wm*32 + mf*16 + ((lane >> 4) << 2);        // local k, + r
    const int kg = k0 + kl;                                   // global k
    float bi[4], bg[4], bo[4];
    #pragma unroll
    for (int r = 0; r < 4; r++){
      bi[r] = b_ih[kg + r]        + b_hh[kg + r];
      bg[r] = b_ih[1024 + kg + r] + b_hh[1024 + kg + r];
      bo[r] = b_ih[1536 + kg + r] + b_hh[1536 + kg + r];
    }
    #pragma unroll
    for (int nf = 0; nf < 4; nf++){
      const int nl = wn*64 + nf*16 + l15;                     // local n'
      float4 hv;
      float h[4];
      #pragma unroll
      for (int r = 0; r < 4; r++){
        float iv = acc[0][mf][nf][r] + bi[r];
        float gv = acc[1][mf][nf][r] + bg[r];
        float ov = acc[2][mf][nf][r] + bo[r];
        float ce = sigf(iv) * tanh_fast(gv);
        h[r] = sigf(ov) * tanh_fast(ce);
      }
      hv.x = h[0]; hv.y = h[1]; hv.z = h[2]; hv.w = h[3];
      *(float4*)(tr + nl*68 + kl) = hv;                       // 16B-aligned
    }
  }
  __syncthreads();

  // store: thread t: k-row = t>>2 (0..63), sub = t&3 covers n'loc [sub*32,+32)
  // -> 4 lanes fill one full 512B k-row run; per-4 n' stay in one b2 (both
  // 320 and n' runs are 4-aligned).
  const int ko  = tid >> 2;
  const int sub = tid & 3;
  const size_t krow_off = (size_t)(k0 + ko)*C_;
  #pragma unroll
  for (int jj = 0; jj < 8; jj++){
    const int nl = sub*32 + jj*4;
    const int ng = nbase + nl;
    const int b2 = ng / 320;                   // const-div -> magic mul
    const int c2 = ng - b2*320;
    float4 v;
    v.x = tr[(nl+0)*68 + ko];
    v.y = tr[(nl+1)*68 + ko];
    v.z = tr[(nl+2)*68 + ko];
    v.w = tr[(nl+3)*68 + ko];
    *(float4*)(out + (size_t)b2*(H_*C_) + krow_off + c2) = v;
  }
}

extern "C" void kernel_launch(void* const* d_in, const int* in_sizes, int n_in,
                              void* d_out, int out_size, void* d_ws, size_t ws_size,
                              hipStream_t stream){
  const float* x    = (const float*)d_in[0];
  const float* w_ih = (const float*)d_in[1];
  // d_in[2] = w_hh is mathematically dead (h0 = 0)
  const float* b_ih = (const float*)d_in[3];
  const float* b_hh = (const float*)d_in[4];
  float* out = (float*)d_out;

  char* ws = (char*)d_ws;
  unsigned short* aws = (unsigned short*)(ws);                           // 1.5 MiB (3*512*512 bf16)
  unsigned short* xws = (unsigned short*)(ws + 2097152);                 // 10 MiB  (10240*512 bf16, n'-layout)
  // total workspace use: ~12 MiB

  k_prep <<<2048, 256, 0, stream>>>(w_ih, x, aws, xws);
  k_gemm <<<640, 256, 0, stream>>>(aws, xws, b_ih, b_hh, out);
}